// Round 17
// baseline (89.133 us; speedup 1.0000x reference)
//
#include <hip/hip_runtime.h>
#include <math.h>

#define P 128
#define T_WIN 480
#define STEPD 20
#define LAG_W 24
#define NITER 10
#define SEG 64
#define PACK 8448          // packed lower-triangular G, rows padded to 4 floats
#define PCHUNK 33          // PACK/256 scan chunks

__device__ __forceinline__ int tri_off(int r) {
  const int a = r >> 2, b = r & 3;
  return ((a + 1) * (2 * a + b)) << 2;
}

// closed-form EWMA constants (geometric series; matches summed fp64 to ~1e-13)
__device__ __forceinline__ void ewma_consts(float af, double& la, float& Sf, float& denomf) {
  const double a = (double)af;
  la = log(a);
  const double A480 = exp(480.0 * la);
  const double S = (1.0 - A480) / (1.0 - a);
  const double Su2 = (1.0 - A480 * A480) / (1.0 - a * a);
  Sf = (float)S;
  denomf = (float)(1.0 - Su2 / (S * S));
}

// ---------------- kernel 1: per-20-day-block outer products (packed write) ----------------
__global__ __launch_bounds__(256) void cblocks_kernel(const float* __restrict__ Y,
                                                      const float* __restrict__ aarg,
                                                      float* __restrict__ cvec,
                                                      float* __restrict__ Call, int K) {
  const int k = blockIdx.x;
  const int tid = threadIdx.x;
  const int ti = tid >> 4, tj = tid & 15;
  __shared__ float st[STEPD][P];
  __shared__ float sbwsm[STEPD];
  if (tid < STEPD) {
    const double la = log((double)aarg[0]);
    sbwsm[tid] = (float)exp(0.5 * (double)(STEPD - 1 - tid) * la);
  }
  __syncthreads();
  const float* __restrict__ Yb = Y + (size_t)k * STEPD * P;
  for (int i = tid; i < STEPD * P / 4; i += 256) {
    float4 v = ((const float4*)Yb)[i];
    const float sw = sbwsm[i >> 5];
    v.x *= sw; v.y *= sw; v.z *= sw; v.w *= sw;
    ((float4*)&st[0][0])[i] = v;
  }
  __syncthreads();

  float acc[8][8];
#pragma unroll
  for (int u = 0; u < 8; ++u)
#pragma unroll
    for (int v = 0; v < 8; ++v) acc[u][v] = 0.0f;

#pragma unroll 4
  for (int t = 0; t < STEPD; ++t) {
    float af[8], bf[8];
    *(float4*)(af)     = *(const float4*)&st[t][ti * 4];
    *(float4*)(af + 4) = *(const float4*)&st[t][64 + ti * 4];
    *(float4*)(bf)     = *(const float4*)&st[t][tj * 4];
    *(float4*)(bf + 4) = *(const float4*)&st[t][64 + tj * 4];
#pragma unroll
    for (int u = 0; u < 8; ++u)
#pragma unroll
      for (int v = 0; v < 8; ++v) acc[u][v] += af[u] * bf[v];
  }

  float* __restrict__ Ck = Call + (size_t)k * PACK;
#pragma unroll
  for (int u = 0; u < 8; ++u) {
    const int r = (u < 4) ? (ti * 4 + u) : (64 + ti * 4 + u - 4);
    const int offr = tri_off(r);
    if (tj * 4 <= r) {
      float4 o0;
      o0.x = acc[u][0]; o0.y = acc[u][1]; o0.z = acc[u][2]; o0.w = acc[u][3];
      *(float4*)(Ck + offr + tj * 4) = o0;
    }
    if (64 + tj * 4 <= r) {
      float4 o1;
      o1.x = acc[u][4]; o1.y = acc[u][5]; o1.z = acc[u][6]; o1.w = acc[u][7];
      *(float4*)(Ck + offr + 64 + tj * 4) = o1;
    }
  }
  if (tid < P) {
    float s = 0.0f;
    for (int t = 0; t < STEPD; ++t) s += sbwsm[t] * st[t][tid];
    cvec[(size_t)k * P + tid] = s;
  }
}

// -------- kernel 1.5: segmented weighted prefix scan, packed G (+ cvec), in place --------
// grid = nseg*PCHUNK blocks for G + ceil(nseg*P/256) blocks for cvec.
__global__ __launch_bounds__(256) void scan_kernel(float* __restrict__ Call,
                                                   float* __restrict__ cvec,
                                                   const float* __restrict__ aarg,
                                                   int nseg, int gblocks) {
  __shared__ float asm_[SEG];
  const int tid = threadIdx.x;
  const int bid = blockIdx.x;
  if (tid < SEG) {
    const double la = log((double)aarg[0]);
    asm_[tid] = (float)exp(-(double)(20 * tid) * la);
  }
  __syncthreads();
  if (bid < gblocks) {
    const int seg = bid / PCHUNK;
    const int chunk = bid - seg * PCHUNK;
    const int e = chunk * 256 + tid;
    float* __restrict__ base = Call + ((size_t)seg * SEG) * PACK + e;
    float g = 0.0f;
#pragma unroll 4
    for (int k = 0; k < SEG; ++k) {
      const float c = base[(size_t)k * PACK];
      g = fmaf(asm_[k], c, g);
      base[(size_t)k * PACK] = g;
    }
  } else {
    const int chain = (bid - gblocks) * 256 + tid;   // (seg, col)
    if (chain < nseg * P) {
      const int seg = chain >> 7;
      const int col = chain & (P - 1);
      float* __restrict__ base = cvec + ((size_t)seg * SEG) * P + col;
      float g = 0.0f;
#pragma unroll 4
      for (int k = 0; k < SEG; ++k) {
        const float c = base[(size_t)k * P];
        g = fmaf(asm_[k], c, g);
        base[(size_t)k * P] = g;
      }
    }
  }
}

// ---- kernel 2: ONE window / 128-thread block; CR-CG; mraw from cvec-prefix ----
__global__ __launch_bounds__(128, 2) void window15_kernel(
    const float* __restrict__ Y, const float* __restrict__ aarg,
    const float* __restrict__ logridge, const float* __restrict__ cvec,
    const float* __restrict__ Gall, float* __restrict__ e_all,
    float* __restrict__ s_all, int W) {
  const int bid = blockIdx.x;
  const int q = W >> 3, r8 = W & 7;
  const int xcd = bid & 7, idx = bid >> 3;
  const int j = ((xcd < r8) ? (xcd * (q + 1)) : (r8 * (q + 1) + (xcd - r8) * q)) + idx;

  const int tid = threadIdx.x;             // 0..127
  const int ti = tid >> 4, tj = tid & 15;  // ti 0..7 -> 16 rows each
  const int lane = tid & 63;
  const int wv = tid >> 6;                 // 0..1
  const int rowbase = ti * 16;

  __shared__ float Gsm[PACK];     // 33.8 KB combined Araw (packed)
  __shared__ float rsm[P];
  __shared__ float vsm[P];
  __shared__ float meansm[P];
  __shared__ float2 gd_wave[2];
  __shared__ float rs_wave[2];
  __shared__ float retd[STEPD];

  double la_d;
  float S, denom;
  ewma_consts(aarg[0], la_d, S, denom);
  const float ridge = expf(logridge[0]);

  // row/col offsets into packed triangle
  int offR[16];
#pragma unroll
  for (int u = 0; u < 16; ++u) offR[u] = tri_off(rowbase + u);
  int colv[8], offC[8];
#pragma unroll
  for (int v = 0; v < 8; ++v) {
    colv[v] = (v < 4) ? (tj * 4 + v) : (64 + tj * 4 + (v - 4));
    offC[v] = tri_off(colv[v]);
  }

  // ---- G-difference plan (shared by Araw and mraw) ----
  int mats[3];
  float scls[3];
  int nm = 0;
  {
    const int o1 = j & ~(SEG - 1);
    const int end = j + 23;
    const int b = o1 + SEG;
    const float pA = (float)exp((double)(STEPD * (end - o1)) * la_d);
    if (end < b) {
      mats[nm] = end; scls[nm] = pA; ++nm;
      if (j > o1) { mats[nm] = j - 1; scls[nm] = -pA; ++nm; }
    } else {
      const float pB2 = (float)exp((double)(STEPD * (end - b)) * la_d);
      mats[nm] = b - 1; scls[nm] = pA; ++nm;
      if (j > o1) { mats[nm] = j - 1; scls[nm] = -pA; ++nm; }
      mats[nm] = end; scls[nm] = pB2; ++nm;
    }
  }

  // ---- register-combine packed G streams -> Gsm (one LDS write pass) ----
  {
    float4* __restrict__ Gsm4 = (float4*)Gsm;
    if (nm == 3) {
      const float cf0 = scls[0], cf1 = scls[1], cf2 = scls[2];
      const float4* __restrict__ G0 = (const float4*)(Gall + (size_t)mats[0] * PACK);
      const float4* __restrict__ G1 = (const float4*)(Gall + (size_t)mats[1] * PACK);
      const float4* __restrict__ G2 = (const float4*)(Gall + (size_t)mats[2] * PACK);
      for (int i = tid; i < PACK / 4; i += 128) {
        const float4 a0 = G0[i];
        const float4 a1 = G1[i];
        const float4 a2 = G2[i];
        float4 o;
        o.x = cf0 * a0.x + cf1 * a1.x + cf2 * a2.x;
        o.y = cf0 * a0.y + cf1 * a1.y + cf2 * a2.y;
        o.z = cf0 * a0.z + cf1 * a1.z + cf2 * a2.z;
        o.w = cf0 * a0.w + cf1 * a1.w + cf2 * a2.w;
        Gsm4[i] = o;
      }
    } else {
      const float cf0 = scls[0];
      const float cf1 = (nm > 1) ? scls[1] : 0.0f;
      const float4* __restrict__ G0 = (const float4*)(Gall + (size_t)mats[0] * PACK);
      const float4* __restrict__ G1 = (const float4*)(Gall + (size_t)mats[(nm > 1) ? 1 : 0] * PACK);
      for (int i = tid; i < PACK / 4; i += 128) {
        const float4 a0 = G0[i];
        const float4 a1 = G1[i];
        float4 o;
        o.x = cf0 * a0.x + cf1 * a1.x;
        o.y = cf0 * a0.y + cf1 * a1.y;
        o.z = cf0 * a0.z + cf1 * a1.z;
        o.w = cf0 * a0.w + cf1 * a1.w;
        Gsm4[i] = o;
      }
    }
  }

  // ---- mraw from scanned cvec: same plan, 2-3 coalesced reads ----
  {
    float s = 0.0f;
    for (int m = 0; m < nm; ++m)
      s += scls[m] * cvec[(size_t)mats[m] * P + tid];
    meansm[tid] = s;
    rsm[tid] = 1.0f;   // r_0 = b = ones
  }
  __syncthreads();

  // ---- single symmetric read into acc + M-build ----
  float acc[16][8];
  {
    const float sc1 = 1.0f / (S * denom);
    const float sc2 = 1.0f / (S * S * denom);
#pragma unroll
    for (int u = 0; u < 16; ++u) {
      const int r = rowbase + u;
      const int offr = offR[u];
      const float mr = meansm[r] * sc2;
#pragma unroll
      for (int v = 0; v < 8; ++v) {
        const int c = colv[v];
        const int idxe = (c <= r) ? (offr + c) : (offC[v] + r);
        float mval = Gsm[idxe] * sc1 - mr * meansm[c];
        if (r == c) mval += ridge;
        acc[u][v] = mval;
      }
    }
  }
  __syncthreads();

  // ---- single-reduction CG (Chronopoulos-Gear): solve M v = 1 ----
  float xo = 0.0f, ro = 1.0f, po = 0.0f, so = 0.0f;
  float gam_old = 1.0f, alp_old = 1.0f;

  for (int it = 0; it < NITER; ++it) {
    const float4 p0 = *(const float4*)&rsm[tj * 4];
    const float4 p1 = *(const float4*)&rsm[64 + tj * 4];
    float pv[8] = {p0.x, p0.y, p0.z, p0.w, p1.x, p1.y, p1.z, p1.w};
    float ap[16];
#pragma unroll
    for (int u = 0; u < 16; ++u) {
      float s = 0.0f;
#pragma unroll
      for (int v = 0; v < 8; ++v) s += acc[u][v] * pv[v];
      ap[u] = s;
    }
#pragma unroll
    for (int m = 1; m <= 8; m <<= 1) {
#pragma unroll
      for (int u = 0; u < 16; ++u) ap[u] += __shfl_xor(ap[u], m);
    }
    // w[tid] = ap[tj] on this very thread (row tid = rowbase + tj) — register select
    float wv_c = ap[0];
#pragma unroll
    for (int u = 1; u < 16; ++u) wv_c = (tj == u) ? ap[u] : wv_c;

    // gp/dp on ALL lanes: broadcast float4 reads of rsm rows (free broadcast)
    {
      const float4 r0 = *(const float4*)&rsm[rowbase];
      const float4 r1 = *(const float4*)&rsm[rowbase + 4];
      const float4 r2 = *(const float4*)&rsm[rowbase + 8];
      const float4 r3 = *(const float4*)&rsm[rowbase + 12];
      const float rv[16] = {r0.x, r0.y, r0.z, r0.w, r1.x, r1.y, r1.z, r1.w,
                            r2.x, r2.y, r2.z, r2.w, r3.x, r3.y, r3.z, r3.w};
      float gp = 0.0f, dp = 0.0f;
#pragma unroll
      for (int u = 0; u < 16; ++u) {
        gp = fmaf(rv[u], rv[u], gp);
        dp = fmaf(ap[u], rv[u], dp);
      }
      gp += __shfl_down(gp, 16); dp += __shfl_down(dp, 16);
      gp += __shfl_down(gp, 32); dp += __shfl_down(dp, 32);
      if (lane == 0) { gd_wave[wv].x = gp; gd_wave[wv].y = dp; }
    }
    __syncthreads();  // B1: gd partials visible; rsm reads complete

    const float gam = gd_wave[0].x + gd_wave[1].x;
    const float del = gd_wave[0].y + gd_wave[1].y;
    float bet, alp;
    if (it == 0) { bet = 0.0f; alp = gam / del; }
    else {
      bet = gam / gam_old;
      alp = gam / (del - bet * gam / alp_old);
    }
    gam_old = gam; alp_old = alp;

    po = ro + bet * po;
    so = wv_c + bet * so;
    xo += alp * po;
    ro -= alp * so;
    rsm[tid] = ro;
    __syncthreads();  // B2
  }

  // ---- v, sum(v) ----
  vsm[tid] = xo;
  float sv = xo;
#pragma unroll
  for (int m = 32; m > 0; m >>= 1) sv += __shfl_down(sv, m);
  if (lane == 0) rs_wave[wv] = sv;
  __syncthreads();
  const float sumv = rs_wave[0] + rs_wave[1];

  // ---- test returns ----
  const float* __restrict__ Yte = Y + (size_t)(j + LAG_W) * STEPD * P;
  for (int d = wv; d < STEPD; d += 2) {
    float pp = Yte[(size_t)d * P + lane] * vsm[lane] +
               Yte[(size_t)d * P + 64 + lane] * vsm[64 + lane];
    for (int off = 32; off > 0; off >>= 1) pp += __shfl_down(pp, off);
    if (lane == 0) retd[d] = pp;
  }
  __syncthreads();

  if (tid == 0) {
    const float invs = 1.0f / sumv;
    float e = 0.0f, s = 0.0f;
#pragma unroll
    for (int d = 0; d < STEPD; ++d) {
      const float rr = retd[d] * invs;
      e += rr; s += rr * rr;
    }
    e_all[j] = e;
    s_all[j] = s * (1.0f / (float)STEPD);
  }
}

// ---------------- fallback: per-window full recompute (self-sufficient) ----------------
__global__ __launch_bounds__(256, 2) void window_fallback(
    const float* __restrict__ Y, const float* __restrict__ aarg,
    const float* __restrict__ logridge, float* __restrict__ e_all,
    float* __restrict__ s_all, int W) {
  const int j = blockIdx.x;
  const int tid = threadIdx.x;
  const int ti = tid >> 4;
  const int tj = tid & 15;

  __shared__ float Msm[P][P + 1];
  __shared__ float wsm[T_WIN];
  __shared__ float swsm[T_WIN];
  __shared__ float meansm[P];
  __shared__ float red[256];
  __shared__ float retd[STEPD];
  __shared__ float zsm[P];
  __shared__ float vsm[P];
  __shared__ float bsm[P];

  float* stage = &Msm[0][0];

  double la;
  float S, denom;
  ewma_consts(aarg[0], la, S, denom);
  for (int t = tid; t < T_WIN; t += 256) {
    const double wn = exp((double)(T_WIN - 1 - t) * la) / (double)S * (double)T_WIN;
    wsm[t] = (float)wn;
    swsm[t] = (float)sqrt(wn);
  }
  if (tid < P) bsm[tid] = 1.0f;
  const float ridge = expf(logridge[0]);
  __syncthreads();

  const float* __restrict__ Ywin = Y + (size_t)j * STEPD * P;
  {
    const int col = tid & 127;
    const int half = tid >> 7;
    float m = 0.0f;
    const int t0 = half * (T_WIN / 2), t1 = t0 + T_WIN / 2;
    for (int t = t0; t < t1; ++t) m += wsm[t] * Ywin[(size_t)t * P + col];
    red[tid] = m;
    __syncthreads();
    if (tid < P) meansm[tid] = (red[tid] + red[tid + 128]) * (1.0f / (float)T_WIN);
    __syncthreads();
  }

  float acc[8][8];
#pragma unroll
  for (int u = 0; u < 8; ++u)
#pragma unroll
    for (int v = 0; v < 8; ++v) acc[u][v] = 0.0f;

  for (int c = 0; c < T_WIN / 32; ++c) {
    __syncthreads();
#pragma unroll
    for (int i = 0; i < 4; ++i) {
      const int idx = i * 1024 + tid * 4;
      float4 v = *(const float4*)(Ywin + (size_t)c * 32 * P + idx);
      const float sw = swsm[c * 32 + (idx >> 7)];
      v.x *= sw; v.y *= sw; v.z *= sw; v.w *= sw;
      *(float4*)(stage + idx) = v;
    }
    __syncthreads();
#pragma unroll 4
    for (int t = 0; t < 32; ++t) {
      const float* rowp = stage + t * P;
      float af[8], bf[8];
      *(float4*)(af) = *(const float4*)(rowp + ti * 8);
      *(float4*)(af + 4) = *(const float4*)(rowp + ti * 8 + 4);
      *(float4*)(bf) = *(const float4*)(rowp + tj * 8);
      *(float4*)(bf + 4) = *(const float4*)(rowp + tj * 8 + 4);
#pragma unroll
      for (int u = 0; u < 8; ++u)
#pragma unroll
        for (int v = 0; v < 8; ++v) acc[u][v] += af[u] * bf[v];
    }
  }
  __syncthreads();

  const float invTd = 1.0f / ((float)T_WIN * denom);
#pragma unroll
  for (int u = 0; u < 8; ++u) {
    const int r = ti * 8 + u;
    const float mr = meansm[r];
#pragma unroll
    for (int v = 0; v < 8; ++v) {
      const int cc = tj * 8 + v;
      float m = (acc[u][v] - (float)T_WIN * mr * meansm[cc]) * invTd;
      if (r == cc) m += ridge;
      Msm[r][cc] = m;
    }
  }
  __syncthreads();

  for (int k = 0; k < P; ++k) {
    const float dkk = Msm[k][k];
    const float sq = sqrtf(dkk);
    const float invd = 1.0f / sq;
    if (tid == 0) Msm[k][k] = sq;
    const int i = k + 1 + tid;
    if (i < P) Msm[i][k] *= invd;
    __syncthreads();
    const int nrem = P - 1 - k;
    for (int ii = ti; ii < nrem; ii += 16) {
      const int ri = k + 1 + ii;
      const float Lik = Msm[ri][k];
      for (int jj = tj; jj < nrem; jj += 16) {
        const int cj = k + 1 + jj;
        Msm[ri][cj] -= Lik * Msm[cj][k];
      }
    }
    __syncthreads();
  }

  for (int k = 0; k < P; ++k) {
    const float zk = bsm[k] / Msm[k][k];
    if (tid == 0) zsm[k] = zk;
    const int i = k + 1 + tid;
    if (i < P) bsm[i] -= Msm[i][k] * zk;
    __syncthreads();
  }
  for (int k = P - 1; k >= 0; --k) {
    const float vk = zsm[k] / Msm[k][k];
    if (tid == 0) vsm[k] = vk;
    if (tid < k) zsm[tid] -= Msm[k][tid] * vk;
    __syncthreads();
  }

  red[tid] = (tid < P) ? vsm[tid] : 0.0f;
  __syncthreads();
  for (int off = 128; off > 0; off >>= 1) {
    if (tid < off) red[tid] += red[tid + off];
    __syncthreads();
  }

  const float* __restrict__ Yte = Y + (size_t)(j + LAG_W) * STEPD * P;
  const int wv = tid >> 6;
  const int lane = tid & 63;
  for (int d = wv; d < STEPD; d += 4) {
    float pp = Yte[(size_t)d * P + lane] * vsm[lane] +
               Yte[(size_t)d * P + 64 + lane] * vsm[64 + lane];
    for (int off = 32; off > 0; off >>= 1) pp += __shfl_down(pp, off);
    if (lane == 0) retd[d] = pp;
  }
  __syncthreads();

  if (tid == 0) {
    const float invs = 1.0f / red[0];
    float e = 0.0f, s = 0.0f;
#pragma unroll
    for (int d = 0; d < STEPD; ++d) {
      const float r = retd[d] * invs;
      e += r;
      s += r * r;
    }
    e_all[j] = e;
    s_all[j] = s * (1.0f / (float)STEPD);
  }
}

// ---------------- kernel 3: final reduction ----------------
__global__ __launch_bounds__(256) void final_kernel(const float* __restrict__ e_all,
                                                    const float* __restrict__ s_all,
                                                    float* __restrict__ out, int W) {
  __shared__ float r1[256], r2[256];
  const int tid = threadIdx.x;
  float e = 0.0f, s = 0.0f;
  for (int i = tid; i < W; i += 256) {
    e += e_all[i];
    s += s_all[i];
  }
  r1[tid] = e;
  r2[tid] = s;
  __syncthreads();
  for (int off = 128; off > 0; off >>= 1) {
    if (tid < off) {
      r1[tid] += r1[tid + off];
      r2[tid] += r2[tid + off];
    }
    __syncthreads();
  }
  if (tid == 0) {
    const float vol = sqrtf(r2[0] / (float)W * 252.0f);
    const float mu = r1[0] / (float)W / (float)STEPD * 252.0f;
    out[0] = vol;
    out[1] = mu;
    out[2] = mu / vol;
  }
}

extern "C" void kernel_launch(void* const* d_in, const int* in_sizes, int n_in,
                              void* d_out, int out_size, void* d_ws, size_t ws_size,
                              hipStream_t stream) {
  const float* Y = (const float*)d_in[0];
  const float* a = (const float*)d_in[1];
  const float* logridge = (const float*)d_in[2];
  float* out = (float*)d_out;

  const int n = in_sizes[0] / P;     // 20480 days
  const int K = n / STEPD;           // 1024 blocks
  const int W = K - LAG_W;           // 1000 windows

  float* ws = (float*)d_ws;
  float* e_all = ws;                          // W (<=1024)
  float* s_all = ws + 1024;                   // W
  float* cvec = ws + 2048;                    // K*128 (scanned in place)
  float* Gall = ws + 2048 + (size_t)K * P;    // K*PACK (packed C, scanned in place)

  const size_t need = ((size_t)2048 + (size_t)K * P + (size_t)K * PACK) * sizeof(float);

  if (ws_size >= need && (n % STEPD) == 0 && W > 0 && W <= 1024 && (K % SEG) == 0) {
    const int nseg = K / SEG;
    const int gblocks = nseg * PCHUNK;
    const int cblocks2 = (nseg * P + 255) / 256;
    cblocks_kernel<<<K, 256, 0, stream>>>(Y, a, cvec, Gall, K);
    scan_kernel<<<gblocks + cblocks2, 256, 0, stream>>>(Gall, cvec, a, nseg, gblocks);
    window15_kernel<<<W, 128, 0, stream>>>(Y, a, logridge, cvec, Gall, e_all, s_all, W);
  } else {
    window_fallback<<<W, 256, 0, stream>>>(Y, a, logridge, e_all, s_all, W);
  }
  final_kernel<<<1, 256, 0, stream>>>(e_all, s_all, out, W);
}

// Round 18
// 77.892 us; speedup vs baseline: 1.1443x; 1.1443x over previous
//
#include <hip/hip_runtime.h>
#include <math.h>

#define P 128
#define T_WIN 480
#define STEPD 20
#define LAG_W 24
#define NITER 10
#define SEG 64
#define PACK 8448          // packed lower-triangular G, rows padded to 4 floats
#define PCHUNK 33          // PACK/256 scan chunks

__device__ __forceinline__ int tri_off(int r) {
  const int a = r >> 2, b = r & 3;
  return ((a + 1) * (2 * a + b)) << 2;
}

// closed-form EWMA constants (geometric series; matches summed fp64 to ~1e-13)
__device__ __forceinline__ void ewma_consts(float af, double& la, float& Sf, float& denomf) {
  const double a = (double)af;
  la = log(a);
  const double A480 = exp(480.0 * la);
  const double S = (1.0 - A480) / (1.0 - a);
  const double Su2 = (1.0 - A480 * A480) / (1.0 - a * a);
  Sf = (float)S;
  denomf = (float)(1.0 - Su2 / (S * S));
}

// ---------------- kernel 1: per-20-day-block outer products (packed write) ----------------
__global__ __launch_bounds__(256) void cblocks_kernel(const float* __restrict__ Y,
                                                      const float* __restrict__ aarg,
                                                      float* __restrict__ cvec,
                                                      float* __restrict__ Call, int K) {
  const int k = blockIdx.x;
  const int tid = threadIdx.x;
  const int ti = tid >> 4, tj = tid & 15;
  __shared__ float st[STEPD][P];
  __shared__ float sbwsm[STEPD];
  if (tid < STEPD) {
    const double la = log((double)aarg[0]);
    sbwsm[tid] = (float)exp(0.5 * (double)(STEPD - 1 - tid) * la);
  }
  __syncthreads();
  const float* __restrict__ Yb = Y + (size_t)k * STEPD * P;
  for (int i = tid; i < STEPD * P / 4; i += 256) {
    float4 v = ((const float4*)Yb)[i];
    const float sw = sbwsm[i >> 5];
    v.x *= sw; v.y *= sw; v.z *= sw; v.w *= sw;
    ((float4*)&st[0][0])[i] = v;
  }
  __syncthreads();

  float acc[8][8];
#pragma unroll
  for (int u = 0; u < 8; ++u)
#pragma unroll
    for (int v = 0; v < 8; ++v) acc[u][v] = 0.0f;

#pragma unroll 4
  for (int t = 0; t < STEPD; ++t) {
    float af[8], bf[8];
    *(float4*)(af)     = *(const float4*)&st[t][ti * 4];
    *(float4*)(af + 4) = *(const float4*)&st[t][64 + ti * 4];
    *(float4*)(bf)     = *(const float4*)&st[t][tj * 4];
    *(float4*)(bf + 4) = *(const float4*)&st[t][64 + tj * 4];
#pragma unroll
    for (int u = 0; u < 8; ++u)
#pragma unroll
      for (int v = 0; v < 8; ++v) acc[u][v] += af[u] * bf[v];
  }

  float* __restrict__ Ck = Call + (size_t)k * PACK;
#pragma unroll
  for (int u = 0; u < 8; ++u) {
    const int r = (u < 4) ? (ti * 4 + u) : (64 + ti * 4 + u - 4);
    const int offr = tri_off(r);
    if (tj * 4 <= r) {
      float4 o0;
      o0.x = acc[u][0]; o0.y = acc[u][1]; o0.z = acc[u][2]; o0.w = acc[u][3];
      *(float4*)(Ck + offr + tj * 4) = o0;
    }
    if (64 + tj * 4 <= r) {
      float4 o1;
      o1.x = acc[u][4]; o1.y = acc[u][5]; o1.z = acc[u][6]; o1.w = acc[u][7];
      *(float4*)(Ck + offr + 64 + tj * 4) = o1;
    }
  }
  if (tid < P) {
    float s = 0.0f;
    for (int t = 0; t < STEPD; ++t) s += sbwsm[t] * st[t][tid];
    cvec[(size_t)k * P + tid] = s;
  }
}

// ---------------- kernel 1.5: segmented weighted prefix scan (packed, in place) ----------------
__global__ __launch_bounds__(256) void scan_kernel(float* __restrict__ Call,
                                                   const float* __restrict__ aarg) {
  __shared__ float asm_[SEG];
  const int tid = threadIdx.x;
  const int seg = blockIdx.x / PCHUNK;
  const int chunk = blockIdx.x - seg * PCHUNK;
  if (tid < SEG) {
    const double la = log((double)aarg[0]);
    asm_[tid] = (float)exp(-(double)(20 * tid) * la);
  }
  __syncthreads();
  const int e = chunk * 256 + tid;
  float* __restrict__ base = Call + ((size_t)seg * SEG) * PACK + e;
  float g = 0.0f;
#pragma unroll 4
  for (int k = 0; k < SEG; ++k) {
    const float c = base[(size_t)k * PACK];
    g = fmaf(asm_[k], c, g);
    base[(size_t)k * PACK] = g;
  }
}

// ---- kernel 2: ONE window / 128-thread block; CR-CG; w via register select ----
__global__ __launch_bounds__(128, 2) void window14_kernel(
    const float* __restrict__ Y, const float* __restrict__ aarg,
    const float* __restrict__ logridge, const float* __restrict__ cvec,
    const float* __restrict__ Gall, float* __restrict__ e_all,
    float* __restrict__ s_all, int W) {
  const int bid = blockIdx.x;
  const int q = W >> 3, r8 = W & 7;
  const int xcd = bid & 7, idx = bid >> 3;
  const int j = ((xcd < r8) ? (xcd * (q + 1)) : (r8 * (q + 1) + (xcd - r8) * q)) + idx;

  const int tid = threadIdx.x;             // 0..127
  const int ti = tid >> 4, tj = tid & 15;  // ti 0..7 -> 16 rows each
  const int lane = tid & 63;
  const int wv = tid >> 6;                 // 0..1
  const int rowbase = ti * 16;

  __shared__ float Gsm[PACK];     // 33.8 KB combined Araw (packed)
  __shared__ float rsm[P];
  __shared__ float vsm[P];
  __shared__ float meansm[P];
  __shared__ float coefsm[LAG_W];
  __shared__ float2 gd_wave[2];
  __shared__ float rs_wave[2];
  __shared__ float retd[STEPD];

  double la_d;
  float S, denom;
  ewma_consts(aarg[0], la_d, S, denom);
  const float ridge = expf(logridge[0]);

  if (tid < LAG_W)
    coefsm[tid] = (float)exp((double)(STEPD * (LAG_W - 1 - tid)) * la_d);
  __syncthreads();

  // row/col offsets into packed triangle
  int offR[16];
#pragma unroll
  for (int u = 0; u < 16; ++u) offR[u] = tri_off(rowbase + u);
  int colv[8], offC[8];
#pragma unroll
  for (int v = 0; v < 8; ++v) {
    colv[v] = (v < 4) ? (tj * 4 + v) : (64 + tj * 4 + (v - 4));
    offC[v] = tri_off(colv[v]);
  }

  // ---- G-difference plan ----
  int mats[3];
  float scls[3];
  int nm = 0;
  {
    const int o1 = j & ~(SEG - 1);
    const int end = j + 23;
    const int b = o1 + SEG;
    const float pA = (float)exp((double)(STEPD * (end - o1)) * la_d);
    if (end < b) {
      mats[nm] = end; scls[nm] = pA; ++nm;
      if (j > o1) { mats[nm] = j - 1; scls[nm] = -pA; ++nm; }
    } else {
      const float pB2 = (float)exp((double)(STEPD * (end - b)) * la_d);
      mats[nm] = b - 1; scls[nm] = pA; ++nm;
      if (j > o1) { mats[nm] = j - 1; scls[nm] = -pA; ++nm; }
      mats[nm] = end; scls[nm] = pB2; ++nm;
    }
  }

  // ---- register-combine packed G streams -> Gsm (one LDS write pass) ----
  {
    float4* __restrict__ Gsm4 = (float4*)Gsm;
    if (nm == 3) {
      const float cf0 = scls[0], cf1 = scls[1], cf2 = scls[2];
      const float4* __restrict__ G0 = (const float4*)(Gall + (size_t)mats[0] * PACK);
      const float4* __restrict__ G1 = (const float4*)(Gall + (size_t)mats[1] * PACK);
      const float4* __restrict__ G2 = (const float4*)(Gall + (size_t)mats[2] * PACK);
      for (int i = tid; i < PACK / 4; i += 128) {
        const float4 a0 = G0[i];
        const float4 a1 = G1[i];
        const float4 a2 = G2[i];
        float4 o;
        o.x = cf0 * a0.x + cf1 * a1.x + cf2 * a2.x;
        o.y = cf0 * a0.y + cf1 * a1.y + cf2 * a2.y;
        o.z = cf0 * a0.z + cf1 * a1.z + cf2 * a2.z;
        o.w = cf0 * a0.w + cf1 * a1.w + cf2 * a2.w;
        Gsm4[i] = o;
      }
    } else {
      const float cf0 = scls[0];
      const float cf1 = (nm > 1) ? scls[1] : 0.0f;
      const float4* __restrict__ G0 = (const float4*)(Gall + (size_t)mats[0] * PACK);
      const float4* __restrict__ G1 = (const float4*)(Gall + (size_t)mats[(nm > 1) ? 1 : 0] * PACK);
      for (int i = tid; i < PACK / 4; i += 128) {
        const float4 a0 = G0[i];
        const float4 a1 = G1[i];
        float4 o;
        o.x = cf0 * a0.x + cf1 * a1.x;
        o.y = cf0 * a0.y + cf1 * a1.y;
        o.z = cf0 * a0.z + cf1 * a1.z;
        o.w = cf0 * a0.w + cf1 * a1.w;
        Gsm4[i] = o;
      }
    }
  }

  // ---- mraw: all 128 threads (overlaps with G loads above) ----
  {
    float s = 0.0f;
    for (int m = 0; m < LAG_W; ++m) s += coefsm[m] * cvec[(size_t)(j + m) * P + tid];
    meansm[tid] = s;
    rsm[tid] = 1.0f;   // r_0 = b = ones
  }
  __syncthreads();

  // ---- single symmetric read into acc + M-build ----
  float acc[16][8];
  {
    const float sc1 = 1.0f / (S * denom);
    const float sc2 = 1.0f / (S * S * denom);
#pragma unroll
    for (int u = 0; u < 16; ++u) {
      const int r = rowbase + u;
      const int offr = offR[u];
      const float mr = meansm[r] * sc2;
#pragma unroll
      for (int v = 0; v < 8; ++v) {
        const int c = colv[v];
        const int idxe = (c <= r) ? (offr + c) : (offC[v] + r);
        float mval = Gsm[idxe] * sc1 - mr * meansm[c];
        if (r == c) mval += ridge;
        acc[u][v] = mval;
      }
    }
  }
  __syncthreads();

  // ---- single-reduction CG (Chronopoulos-Gear): solve M v = 1 ----
  float xo = 0.0f, ro = 1.0f, po = 0.0f, so = 0.0f;
  float gam_old = 1.0f, alp_old = 1.0f;

  for (int it = 0; it < NITER; ++it) {
    const float4 p0 = *(const float4*)&rsm[tj * 4];
    const float4 p1 = *(const float4*)&rsm[64 + tj * 4];
    float pv[8] = {p0.x, p0.y, p0.z, p0.w, p1.x, p1.y, p1.z, p1.w};
    float ap[16];
#pragma unroll
    for (int u = 0; u < 16; ++u) {
      float s = 0.0f;
#pragma unroll
      for (int v = 0; v < 8; ++v) s += acc[u][v] * pv[v];
      ap[u] = s;
    }
#pragma unroll
    for (int m = 1; m <= 8; m <<= 1) {
#pragma unroll
      for (int u = 0; u < 16; ++u) ap[u] += __shfl_xor(ap[u], m);
    }
    // w[tid] = ap[tj] on this very thread (row tid = rowbase + tj) — register select
    float wv_c = ap[0];
#pragma unroll
    for (int u = 1; u < 16; ++u) wv_c = (tj == u) ? ap[u] : wv_c;

    // gp/dp on ALL lanes: broadcast float4 reads of rsm rows (free broadcast)
    {
      const float4 r0 = *(const float4*)&rsm[rowbase];
      const float4 r1 = *(const float4*)&rsm[rowbase + 4];
      const float4 r2 = *(const float4*)&rsm[rowbase + 8];
      const float4 r3 = *(const float4*)&rsm[rowbase + 12];
      const float rv[16] = {r0.x, r0.y, r0.z, r0.w, r1.x, r1.y, r1.z, r1.w,
                            r2.x, r2.y, r2.z, r2.w, r3.x, r3.y, r3.z, r3.w};
      float gp = 0.0f, dp = 0.0f;
#pragma unroll
      for (int u = 0; u < 16; ++u) {
        gp = fmaf(rv[u], rv[u], gp);
        dp = fmaf(ap[u], rv[u], dp);
      }
      gp += __shfl_down(gp, 16); dp += __shfl_down(dp, 16);
      gp += __shfl_down(gp, 32); dp += __shfl_down(dp, 32);
      if (lane == 0) { gd_wave[wv].x = gp; gd_wave[wv].y = dp; }
    }
    __syncthreads();  // B1: gd partials visible; rsm reads complete

    const float gam = gd_wave[0].x + gd_wave[1].x;
    const float del = gd_wave[0].y + gd_wave[1].y;
    float bet, alp;
    if (it == 0) { bet = 0.0f; alp = gam / del; }
    else {
      bet = gam / gam_old;
      alp = gam / (del - bet * gam / alp_old);
    }
    gam_old = gam; alp_old = alp;

    po = ro + bet * po;
    so = wv_c + bet * so;
    xo += alp * po;
    ro -= alp * so;
    rsm[tid] = ro;
    __syncthreads();  // B2
  }

  // ---- v, sum(v) ----
  vsm[tid] = xo;
  float sv = xo;
#pragma unroll
  for (int m = 32; m > 0; m >>= 1) sv += __shfl_down(sv, m);
  if (lane == 0) rs_wave[wv] = sv;
  __syncthreads();
  const float sumv = rs_wave[0] + rs_wave[1];

  // ---- test returns ----
  const float* __restrict__ Yte = Y + (size_t)(j + LAG_W) * STEPD * P;
  for (int d = wv; d < STEPD; d += 2) {
    float pp = Yte[(size_t)d * P + lane] * vsm[lane] +
               Yte[(size_t)d * P + 64 + lane] * vsm[64 + lane];
    for (int off = 32; off > 0; off >>= 1) pp += __shfl_down(pp, off);
    if (lane == 0) retd[d] = pp;
  }
  __syncthreads();

  if (tid == 0) {
    const float invs = 1.0f / sumv;
    float e = 0.0f, s = 0.0f;
#pragma unroll
    for (int d = 0; d < STEPD; ++d) {
      const float rr = retd[d] * invs;
      e += rr; s += rr * rr;
    }
    e_all[j] = e;
    s_all[j] = s * (1.0f / (float)STEPD);
  }
}

// ---------------- fallback: per-window full recompute (self-sufficient) ----------------
__global__ __launch_bounds__(256, 2) void window_fallback(
    const float* __restrict__ Y, const float* __restrict__ aarg,
    const float* __restrict__ logridge, float* __restrict__ e_all,
    float* __restrict__ s_all, int W) {
  const int j = blockIdx.x;
  const int tid = threadIdx.x;
  const int ti = tid >> 4;
  const int tj = tid & 15;

  __shared__ float Msm[P][P + 1];
  __shared__ float wsm[T_WIN];
  __shared__ float swsm[T_WIN];
  __shared__ float meansm[P];
  __shared__ float red[256];
  __shared__ float retd[STEPD];
  __shared__ float zsm[P];
  __shared__ float vsm[P];
  __shared__ float bsm[P];

  float* stage = &Msm[0][0];

  double la;
  float S, denom;
  ewma_consts(aarg[0], la, S, denom);
  for (int t = tid; t < T_WIN; t += 256) {
    const double wn = exp((double)(T_WIN - 1 - t) * la) / (double)S * (double)T_WIN;
    wsm[t] = (float)wn;
    swsm[t] = (float)sqrt(wn);
  }
  if (tid < P) bsm[tid] = 1.0f;
  const float ridge = expf(logridge[0]);
  __syncthreads();

  const float* __restrict__ Ywin = Y + (size_t)j * STEPD * P;
  {
    const int col = tid & 127;
    const int half = tid >> 7;
    float m = 0.0f;
    const int t0 = half * (T_WIN / 2), t1 = t0 + T_WIN / 2;
    for (int t = t0; t < t1; ++t) m += wsm[t] * Ywin[(size_t)t * P + col];
    red[tid] = m;
    __syncthreads();
    if (tid < P) meansm[tid] = (red[tid] + red[tid + 128]) * (1.0f / (float)T_WIN);
    __syncthreads();
  }

  float acc[8][8];
#pragma unroll
  for (int u = 0; u < 8; ++u)
#pragma unroll
    for (int v = 0; v < 8; ++v) acc[u][v] = 0.0f;

  for (int c = 0; c < T_WIN / 32; ++c) {
    __syncthreads();
#pragma unroll
    for (int i = 0; i < 4; ++i) {
      const int idx = i * 1024 + tid * 4;
      float4 v = *(const float4*)(Ywin + (size_t)c * 32 * P + idx);
      const float sw = swsm[c * 32 + (idx >> 7)];
      v.x *= sw; v.y *= sw; v.z *= sw; v.w *= sw;
      *(float4*)(stage + idx) = v;
    }
    __syncthreads();
#pragma unroll 4
    for (int t = 0; t < 32; ++t) {
      const float* rowp = stage + t * P;
      float af[8], bf[8];
      *(float4*)(af) = *(const float4*)(rowp + ti * 8);
      *(float4*)(af + 4) = *(const float4*)(rowp + ti * 8 + 4);
      *(float4*)(bf) = *(const float4*)(rowp + tj * 8);
      *(float4*)(bf + 4) = *(const float4*)(rowp + tj * 8 + 4);
#pragma unroll
      for (int u = 0; u < 8; ++u)
#pragma unroll
        for (int v = 0; v < 8; ++v) acc[u][v] += af[u] * bf[v];
    }
  }
  __syncthreads();

  const float invTd = 1.0f / ((float)T_WIN * denom);
#pragma unroll
  for (int u = 0; u < 8; ++u) {
    const int r = ti * 8 + u;
    const float mr = meansm[r];
#pragma unroll
    for (int v = 0; v < 8; ++v) {
      const int cc = tj * 8 + v;
      float m = (acc[u][v] - (float)T_WIN * mr * meansm[cc]) * invTd;
      if (r == cc) m += ridge;
      Msm[r][cc] = m;
    }
  }
  __syncthreads();

  for (int k = 0; k < P; ++k) {
    const float dkk = Msm[k][k];
    const float sq = sqrtf(dkk);
    const float invd = 1.0f / sq;
    if (tid == 0) Msm[k][k] = sq;
    const int i = k + 1 + tid;
    if (i < P) Msm[i][k] *= invd;
    __syncthreads();
    const int nrem = P - 1 - k;
    for (int ii = ti; ii < nrem; ii += 16) {
      const int ri = k + 1 + ii;
      const float Lik = Msm[ri][k];
      for (int jj = tj; jj < nrem; jj += 16) {
        const int cj = k + 1 + jj;
        Msm[ri][cj] -= Lik * Msm[cj][k];
      }
    }
    __syncthreads();
  }

  for (int k = 0; k < P; ++k) {
    const float zk = bsm[k] / Msm[k][k];
    if (tid == 0) zsm[k] = zk;
    const int i = k + 1 + tid;
    if (i < P) bsm[i] -= Msm[i][k] * zk;
    __syncthreads();
  }
  for (int k = P - 1; k >= 0; --k) {
    const float vk = zsm[k] / Msm[k][k];
    if (tid == 0) vsm[k] = vk;
    if (tid < k) zsm[tid] -= Msm[k][tid] * vk;
    __syncthreads();
  }

  red[tid] = (tid < P) ? vsm[tid] : 0.0f;
  __syncthreads();
  for (int off = 128; off > 0; off >>= 1) {
    if (tid < off) red[tid] += red[tid + off];
    __syncthreads();
  }

  const float* __restrict__ Yte = Y + (size_t)(j + LAG_W) * STEPD * P;
  const int wv = tid >> 6;
  const int lane = tid & 63;
  for (int d = wv; d < STEPD; d += 4) {
    float pp = Yte[(size_t)d * P + lane] * vsm[lane] +
               Yte[(size_t)d * P + 64 + lane] * vsm[64 + lane];
    for (int off = 32; off > 0; off >>= 1) pp += __shfl_down(pp, off);
    if (lane == 0) retd[d] = pp;
  }
  __syncthreads();

  if (tid == 0) {
    const float invs = 1.0f / red[0];
    float e = 0.0f, s = 0.0f;
#pragma unroll
    for (int d = 0; d < STEPD; ++d) {
      const float r = retd[d] * invs;
      e += r;
      s += r * r;
    }
    e_all[j] = e;
    s_all[j] = s * (1.0f / (float)STEPD);
  }
}

// ---------------- kernel 3: final reduction ----------------
__global__ __launch_bounds__(256) void final_kernel(const float* __restrict__ e_all,
                                                    const float* __restrict__ s_all,
                                                    float* __restrict__ out, int W) {
  __shared__ float r1[256], r2[256];
  const int tid = threadIdx.x;
  float e = 0.0f, s = 0.0f;
  for (int i = tid; i < W; i += 256) {
    e += e_all[i];
    s += s_all[i];
  }
  r1[tid] = e;
  r2[tid] = s;
  __syncthreads();
  for (int off = 128; off > 0; off >>= 1) {
    if (tid < off) {
      r1[tid] += r1[tid + off];
      r2[tid] += r2[tid + off];
    }
    __syncthreads();
  }
  if (tid == 0) {
    const float vol = sqrtf(r2[0] / (float)W * 252.0f);
    const float mu = r1[0] / (float)W / (float)STEPD * 252.0f;
    out[0] = vol;
    out[1] = mu;
    out[2] = mu / vol;
  }
}

extern "C" void kernel_launch(void* const* d_in, const int* in_sizes, int n_in,
                              void* d_out, int out_size, void* d_ws, size_t ws_size,
                              hipStream_t stream) {
  const float* Y = (const float*)d_in[0];
  const float* a = (const float*)d_in[1];
  const float* logridge = (const float*)d_in[2];
  float* out = (float*)d_out;

  const int n = in_sizes[0] / P;     // 20480 days
  const int K = n / STEPD;           // 1024 blocks
  const int W = K - LAG_W;           // 1000 windows

  float* ws = (float*)d_ws;
  float* e_all = ws;                          // W (<=1024)
  float* s_all = ws + 1024;                   // W
  float* cvec = ws + 2048;                    // K*128
  float* Gall = ws + 2048 + (size_t)K * P;    // K*PACK (packed C, scanned in place)

  const size_t need = ((size_t)2048 + (size_t)K * P + (size_t)K * PACK) * sizeof(float);

  if (ws_size >= need && (n % STEPD) == 0 && W > 0 && W <= 1024 && (K % SEG) == 0) {
    cblocks_kernel<<<K, 256, 0, stream>>>(Y, a, cvec, Gall, K);
    scan_kernel<<<(K / SEG) * PCHUNK, 256, 0, stream>>>(Gall, a);
    window14_kernel<<<W, 128, 0, stream>>>(Y, a, logridge, cvec, Gall, e_all, s_all, W);
  } else {
    window_fallback<<<W, 256, 0, stream>>>(Y, a, logridge, e_all, s_all, W);
    final_kernel<<<1, 256, 0, stream>>>(e_all, s_all, out, W);
    return;
  }
  final_kernel<<<1, 256, 0, stream>>>(e_all, s_all, out, W);
}